// Round 7
// baseline (319.416 us; speedup 1.0000x reference)
//
#include <hip/hip_runtime.h>
#include <hip/hip_bf16.h>

#define T_    1024
#define TP    1028   // T + 4 (pad 2 each side)

typedef __attribute__((ext_vector_type(8))) short short8;
typedef __attribute__((ext_vector_type(4))) float floatx4;

__device__ __forceinline__ unsigned short f2bf(float f) {
  union { float f; unsigned u; } x; x.f = f;
  unsigned r = x.u + 0x7FFFu + ((x.u >> 16) & 1u);
  return (unsigned short)(r >> 16);
}
__device__ __forceinline__ float bf2f(unsigned short u) {
  union { unsigned u; float f; } x; x.u = ((unsigned)u) << 16;
  return x.f;
}

// ---------------- pad + cast hs_pad (B,T,512) f32 -> (B,T+4,512) bf16, zero borders
__global__ __launch_bounds__(256) void k_pad_cast(const float* __restrict__ hs,
                                                  unsigned short* __restrict__ xp) {
  size_t i = (size_t)blockIdx.x * 256 + threadIdx.x;
  size_t e = i * 8;
  int c = (int)(e & 511);
  size_t rb = e >> 9;
  int r = (int)(rb % TP);
  int b = (int)(rb / TP);
  int t = r - 2;
  short8 v;
  if (t >= 0 && t < T_) {
    const float* src = hs + (((size_t)b * T_ + t) << 9) + c;
    #pragma unroll
    for (int j = 0; j < 8; j++) v[j] = (short)f2bf(src[j]);
  } else {
    #pragma unroll
    for (int j = 0; j < 8; j++) v[j] = 0;
  }
  *(short8*)(xp + e) = v;
}

// ---------------- merged prep: w1 cast | w2 cast | conv_w transpose-cast |
// bias fold | inverse table. Partitioned by blockIdx (saves 4 dispatches).
__global__ __launch_bounds__(256) void k_prep(
    const float* __restrict__ w1, const float* __restrict__ w2,
    const float* __restrict__ cw, const float* __restrict__ cb,
    const float* __restrict__ b1, const int* __restrict__ pal,
    unsigned short* __restrict__ w1b, unsigned short* __restrict__ w2b,
    unsigned short* __restrict__ cwT, float* __restrict__ bc,
    unsigned short* __restrict__ inv) {
  __shared__ float tile[32][33];     // used by tcast branch only
  __shared__ int scnt[100];          // used by inv branch only
  int b = blockIdx.x, tid = threadIdx.x;
  if (b < 128) {                     // w1 f32->bf16 (512*512)
    size_t e = ((size_t)b * 256 + tid) * 8;
    short8 v;
    #pragma unroll
    for (int j = 0; j < 8; j++) v[j] = (short)f2bf(w1[e + j]);
    *(short8*)(w1b + e) = v;
  } else if (b < 528) {              // w2 f32->bf16 (1600*512)
    size_t e = ((size_t)(b - 128) * 256 + tid) * 8;
    short8 v;
    #pragma unroll
    for (int j = 0; j < 8; j++) v[j] = (short)f2bf(w2[e + j]);
    *(short8*)(w2b + e) = v;
  } else if (b < 1808) {             // cw[j][ki] (512x2560) -> cwT[ki][j] bf16
    int bb = b - 528;
    int bx = bb % 80, by = bb / 80;
    int tx = tid & 31, ty = tid >> 5;
    #pragma unroll
    for (int dy = 0; dy < 4; dy++) {
      int j = by * 32 + ty + dy * 8;
      tile[ty + dy * 8][tx] = cw[(size_t)j * 2560 + bx * 32 + tx];
    }
    __syncthreads();
    #pragma unroll
    for (int dy = 0; dy < 4; dy++) {
      int ki = bx * 32 + ty + dy * 8;
      cwT[(size_t)ki * 512 + by * 32 + tx] = f2bf(tile[tx][ty + dy * 8]);
    }
  } else if (b < 1810) {             // bc[o] = b1[o] + sum_j w1[o][j]*cb[j]
    int o = (b - 1808) * 256 + tid;
    float s = b1[o];
    for (int j = 0; j < 512; j++) s += w1[(size_t)o * 512 + j] * cb[j];
    bc[o] = s;
  } else {                           // inv[p*16+slot] = arc
    if (tid < 100) scnt[tid] = 0;
    __syncthreads();
    for (int a = tid; a < 1600; a += 256) {
      int p = pal[a];
      int slot = atomicAdd(&scnt[p], 1);
      inv[p * 16 + slot] = (unsigned short)a;
    }
  }
}

// ---------------- 128^2 2-phase GEMM (prep GEMM + G2's 64-col tail)
template<int HAS_BIAS>
__global__ __launch_bounds__(256) void k_gemm_bt(
    const unsigned short* __restrict__ A, const unsigned short* __restrict__ Bt,
    const float* __restrict__ bias, unsigned short* __restrict__ C,
    int K, int ldc, int nvalid) {
  __shared__ unsigned short sA[128 * 64];
  __shared__ unsigned short sB[128 * 64];
  int tid  = threadIdx.x;
  int lane = tid & 63;
  int wv   = tid >> 6;
  int wr   = wv >> 1, wc = wv & 1;
  int m0 = blockIdx.x * 128;
  int n0 = blockIdx.y * 128;
  int l15  = lane & 15;
  int l_hi = lane >> 4;
  int srow = (wv << 3) + (lane >> 3);
  int scol = (((lane & 7) ^ ((lane >> 3) & 7)) << 3);
  int rkey = (l15 & 7) << 3;

  floatx4 acc[4][4];
  #pragma unroll
  for (int i = 0; i < 4; i++)
    #pragma unroll
    for (int j = 0; j < 4; j++) acc[i][j] = (floatx4){0.f, 0.f, 0.f, 0.f};

  for (int k0 = 0; k0 < K; k0 += 64) {
    __syncthreads();
    #pragma unroll
    for (int q = 0; q < 4; q++) {
      int r = (q << 5) + srow;
      const unsigned short* ga = A + (size_t)(m0 + r) * K + (k0 + scol);
      __builtin_amdgcn_global_load_lds(
          (const __attribute__((address_space(1))) void*)ga,
          (__attribute__((address_space(3))) void*)(sA + (q << 11) + (wv << 9)),
          16, 0, 0);
      const unsigned short* gb = Bt + (size_t)(n0 + r) * K + (k0 + scol);
      __builtin_amdgcn_global_load_lds(
          (const __attribute__((address_space(1))) void*)gb,
          (__attribute__((address_space(3))) void*)(sB + (q << 11) + (wv << 9)),
          16, 0, 0);
    }
    __syncthreads();
    #pragma unroll
    for (int ks = 0; ks < 2; ks++) {
      int col = ((ks << 5) + (l_hi << 3)) ^ rkey;
      short8 af[4], bfr[4];
      #pragma unroll
      for (int i = 0; i < 4; i++) {
        af[i]  = *(const short8*)(sA + (((wr << 6) + (i << 4) + l15) << 6) + col);
        bfr[i] = *(const short8*)(sB + (((wc << 6) + (i << 4) + l15) << 6) + col);
      }
      #pragma unroll
      for (int i = 0; i < 4; i++)
        #pragma unroll
        for (int j = 0; j < 4; j++)
          acc[i][j] = __builtin_amdgcn_mfma_f32_16x16x32_bf16(af[i], bfr[j], acc[i][j], 0, 0, 0);
    }
  }
  #pragma unroll
  for (int i = 0; i < 4; i++) {
    int row = m0 + (wr << 6) + (i << 4) + (l_hi << 2);
    #pragma unroll
    for (int j = 0; j < 4; j++) {
      int lcol = (wc << 6) + (j << 4) + l15;
      if (lcol < nvalid) {
        float bv = HAS_BIAS ? bias[n0 + lcol] : 0.f;
        #pragma unroll
        for (int jj = 0; jj < 4; jj++)
          C[(size_t)(row + jj) * ldc + n0 + lcol] = f2bf(acc[i][j][jj] + bv);
      }
    }
  }
}

// ---------------- 256^2 8-phase GEMM (T2+T3+T4+T5), C = A * Bt^T + bias
// NT3=0 (G1): bijective XCD swizzle, one tile per block.
// NT3=1 (G2): persistent 3-tile -- 256 blocks (1/CU); block keeps m-panel
// FIXED and loops 3 n-tiles, so tiles 2-3 re-stage A from hot L2 (~200cy)
// instead of cold HBM (~900cy), and 2 of 3 pipeline fills amortize away.
// Decode puts the 2 blocks sharing an m-panel on the same XCD.
// LDS: 8 slots [buf][op][half] of 128x64 bf16, XOR-swizzled; 8 waves (2Mx4N).
// STAGE has NO k clamp: overrun reads (<=2 K-tiles) land in allocated ws.
template<int CONV, int NY, int NT3>
__global__ __launch_bounds__(512, 2) void k_gemm256(
    const unsigned short* __restrict__ A, const unsigned short* __restrict__ Bt,
    const float* __restrict__ bias, unsigned short* __restrict__ C,
    int N, int K) {
  __shared__ unsigned short lds[65536];   // 8 * 8192 u16
  const int tid = threadIdx.x;
  const int lane = tid & 63;
  const int w = tid >> 6;
  const int wm = w >> 2, wn = w & 3;
  const int l15 = lane & 15, l_hi = lane >> 4;
  const int rkey = (l15 & 7) << 3;
  const int bid = blockIdx.x;
  int m0, nh;
  if (NT3) {                       // x = XCD, k = block-within-XCD
    int x = bid & 7, k = bid >> 3;
    m0 = (((x << 4) + (k >> 1))) << 8;     // XCD owns m-tiles [16x,16x+16)
    nh = (k & 1) * 3;                      // n-halves {0,1,2} / {3,4,5}
  } else {
    const int cpx = (int)gridDim.x >> 3;
    const int logical = (bid & 7) * cpx + (bid >> 3);
    m0 = (logical / NY) << 8;
    nh = logical % NY;
  }
  const int nt = K >> 6;

  const int srow = tid >> 3;
  const int scol = (((tid & 7) ^ ((tid >> 3) & 7)) << 3);
  const unsigned short* abase;
  size_t astr;
  if (CONV) {
    int m = m0 + srow;                 // block never crosses a b-boundary (256 | 1024)
    int b = m >> 10, t = m & 1023;
    abase = A + (((size_t)b * TP + t) << 9) + scol;
    astr = 512;                        // im2col: +1 row = +512 elems
  } else {
    abase = A + (size_t)(m0 + srow) * K + scol;
    astr = (size_t)K;
  }
  const unsigned short* bbase = Bt + (size_t)((nh << 8) + srow) * K + scol;
  const size_t bstr = (size_t)K;

  #define SLOT(buf, op, h) ((((((buf) << 1) | (op)) << 1) | (h)) * 8192)

  auto STAGE = [&](int buf, int op, int h, int kt) {
    const unsigned short* g0 = (op ? bbase : abase)
        + (size_t)(h * 128) * (op ? bstr : astr) + (size_t)kt * 64;
    unsigned short* d = lds + SLOT(buf, op, h) + w * 512;
    __builtin_amdgcn_global_load_lds(
        (const __attribute__((address_space(1))) void*)g0,
        (__attribute__((address_space(3))) void*)d, 16, 0, 0);
    __builtin_amdgcn_global_load_lds(
        (const __attribute__((address_space(1))) void*)(g0 + (size_t)64 * (op ? bstr : astr)),
        (__attribute__((address_space(3))) void*)(d + 4096), 16, 0, 0);
  };

  auto RDA = [&](short8* dst, int buf, int rh) {        // 4 row-frags x 2 ks
    const unsigned short* s = lds + SLOT(buf, 0, wm);
    #pragma unroll
    for (int i = 0; i < 4; i++) {
      int row = (((rh << 2) + i) << 4) + l15;
      #pragma unroll
      for (int ks = 0; ks < 2; ks++) {
        int col = (((ks << 5) + (l_hi << 3)) ^ rkey);
        dst[i * 2 + ks] = *(const short8*)(s + (row << 6) + col);
      }
    }
  };
  auto RDB = [&](short8* dst, int buf, int jh) {        // 2 col-frags x 2 ks
    const unsigned short* s = lds + SLOT(buf, 1, (wn >> 1));
    #pragma unroll
    for (int j = 0; j < 2; j++) {
      int row = ((wn & 1) << 6) + (((jh << 1) + j) << 4) + l15;
      #pragma unroll
      for (int ks = 0; ks < 2; ks++) {
        int col = (((ks << 5) + (l_hi << 3)) ^ rkey);
        dst[j * 2 + ks] = *(const short8*)(s + (row << 6) + col);
      }
    }
  };

  #define MMQ(ar, br, rh, ch)                                                  \
    __builtin_amdgcn_s_setprio(1);                                             \
    _Pragma("unroll")                                                          \
    for (int i = 0; i < 4; i++)                                                \
      _Pragma("unroll")                                                        \
      for (int j = 0; j < 2; j++)                                              \
        _Pragma("unroll")                                                      \
        for (int ks = 0; ks < 2; ks++)                                         \
          acc[((rh) << 2) + i][((ch) << 1) + j] =                              \
              __builtin_amdgcn_mfma_f32_16x16x32_bf16(                         \
                  ar[i * 2 + ks], br[j * 2 + ks],                              \
                  acc[((rh) << 2) + i][((ch) << 1) + j], 0, 0, 0);             \
    __builtin_amdgcn_s_setprio(0);

  floatx4 acc[8][4];
  short8 aR[8], bR0[4], bR1[4];

  for (int tt = 0; tt < (NT3 ? 3 : 1); ++tt) {
    const int n0 = NT3 ? ((nh + tt) << 8) : (nh << 8);
    if (NT3) bbase = Bt + (size_t)(n0 + srow) * K + scol;

    #pragma unroll
    for (int i = 0; i < 8; i++)
      #pragma unroll
      for (int j = 0; j < 4; j++) acc[i][j] = (floatx4){0.f, 0.f, 0.f, 0.f};

    // prologue: T0 fully (buf0), T1.B (buf1)
    STAGE(0, 1, 0, 0); STAGE(0, 1, 1, 0); STAGE(0, 0, 0, 0); STAGE(0, 0, 1, 0);
    STAGE(1, 1, 0, 1); STAGE(1, 1, 1, 1);
    asm volatile("s_waitcnt vmcnt(4)" ::: "memory");
    __builtin_amdgcn_s_barrier();

    const int niter = nt >> 1;
    for (int it = 0; it < niter; ++it) {
      const int t0 = it << 1;
      // p1: tile t0 q(0,0)
      RDA(aR, 0, 0); RDB(bR0, 0, 0);
      STAGE(1, 0, 0, t0 + 1);
      __builtin_amdgcn_s_barrier();
      MMQ(aR, bR0, 0, 0);
      __builtin_amdgcn_s_barrier();
      // p2: q(0,1)
      RDB(bR1, 0, 1);
      STAGE(1, 0, 1, t0 + 1);
      __builtin_amdgcn_s_barrier();
      MMQ(aR, bR1, 0, 1);
      __builtin_amdgcn_s_barrier();
      // p3: q(1,0)
      RDA(aR, 0, 1);
      STAGE(0, 1, 0, t0 + 2);
      __builtin_amdgcn_s_barrier();
      MMQ(aR, bR0, 1, 0);
      __builtin_amdgcn_s_barrier();
      // p4: q(1,1)  [+ tile-boundary wait]
      STAGE(0, 1, 1, t0 + 2);
      __builtin_amdgcn_s_barrier();
      MMQ(aR, bR1, 1, 1);
      asm volatile("s_waitcnt vmcnt(4)" ::: "memory");
      __builtin_amdgcn_s_barrier();
      // p5: tile t0+1 q(0,0)
      RDA(aR, 1, 0); RDB(bR0, 1, 0);
      STAGE(0, 0, 0, t0 + 2);
      __builtin_amdgcn_s_barrier();
      MMQ(aR, bR0, 0, 0);
      __builtin_amdgcn_s_barrier();
      // p6: q(0,1)
      RDB(bR1, 1, 1);
      STAGE(0, 0, 1, t0 + 2);
      __builtin_amdgcn_s_barrier();
      MMQ(aR, bR1, 0, 1);
      __builtin_amdgcn_s_barrier();
      // p7: q(1,0)
      RDA(aR, 1, 1);
      STAGE(1, 1, 0, t0 + 3);
      __builtin_amdgcn_s_barrier();
      MMQ(aR, bR0, 1, 0);
      __builtin_amdgcn_s_barrier();
      // p8: q(1,1)  [+ tile-boundary wait]
      STAGE(1, 1, 1, t0 + 3);
      __builtin_amdgcn_s_barrier();
      MMQ(aR, bR1, 1, 1);
      asm volatile("s_waitcnt vmcnt(4)" ::: "memory");
      __builtin_amdgcn_s_barrier();
    }

    // C-write: register-only (no LDS dep) -> safe to overlap with other
    // waves starting next tile's prologue stages.
    #pragma unroll
    for (int i = 0; i < 8; i++) {
      int row = m0 + (wm << 7) + (i << 4) + (l_hi << 2);
      #pragma unroll
      for (int j = 0; j < 4; j++) {
        int col = n0 + (wn << 6) + (j << 4) + l15;
        float bv = bias[col];
        #pragma unroll
        for (int jj = 0; jj < 4; jj++)
          C[(size_t)(row + jj) * N + col] = f2bf(acc[i][j][jj] + bv);
      }
    }
  }
  #undef SLOT
  #undef MMQ
}

// ---------------- fused epilogue (gather form, no atomics)
// Uses group-uniform phone labels (phn[8g..8g+7] all equal, = repeat struct):
// one selp lookup per group instead of 8.
__global__ __launch_bounds__(256) void k_epilogue(
    const unsigned short* __restrict__ Wm, const float* __restrict__ po,
    const int* __restrict__ phn, const unsigned short* __restrict__ inv_g,
    float* __restrict__ out) {
  __shared__ unsigned short sphn[200];   // per-group phone (arc 8g)
  __shared__ unsigned short sinv[1600];
  __shared__ float selp[4][200];
  __shared__ float sarc[4][1600];      // layout [j][200]: index j*200+g
  int tid = threadIdx.x;
  int lane = tid & 63;
  int wv = tid >> 6;
  for (int i = tid; i < 1600; i += 256) sinv[i] = inv_g[i];
  if (tid < 200) sphn[tid] = (unsigned short)phn[tid << 3];
  __syncthreads();
  int m = blockIdx.x * 4 + wv;

  const float* porow = po + (size_t)m * 200;
  float v[4];
  float mx = -1e30f;
  #pragma unroll
  for (int gi = 0; gi < 4; gi++) {
    int g = lane + gi * 64;
    v[gi] = (g < 200) ? porow[g] : -1e30f;
    mx = fmaxf(mx, v[gi]);
  }
  #pragma unroll
  for (int o = 32; o >= 1; o >>= 1) mx = fmaxf(mx, __shfl_xor(mx, o));
  float ev[4];
  float s = 0.f;
  #pragma unroll
  for (int gi = 0; gi < 4; gi++) {
    int g = lane + gi * 64;
    if (g < 200) { ev[gi] = __expf(v[gi] - mx); s += ev[gi]; }
  }
  #pragma unroll
  for (int o = 32; o >= 1; o >>= 1) s += __shfl_xor(s, o);
  float rs = __builtin_amdgcn_rcpf(s);
  #pragma unroll
  for (int gi = 0; gi < 4; gi++) {
    int g = lane + gi * 64;
    if (g < 200) selp[wv][g] = ev[gi] * rs;
  }

  const unsigned short* wrow = Wm + (size_t)m * 1600;
  for (int g = lane; g < 200; g += 64) {
    short8 wb = *(const short8*)(wrow + g * 8);
    float w[8];
    #pragma unroll
    for (int j = 0; j < 8; j++) w[j] = bf2f((unsigned short)wb[j]);
    float gm = w[0];
    #pragma unroll
    for (int j = 1; j < 8; j++) gm = fmaxf(gm, w[j]);
    float ej[8];
    float se = 0.f;
    #pragma unroll
    for (int j = 0; j < 8; j++) { ej[j] = __expf(w[j] - gm); se += ej[j]; }
    float f = selp[wv][sphn[g]] * __builtin_amdgcn_rcpf(se);
    #pragma unroll
    for (int j = 0; j < 8; j++)
      sarc[wv][j * 200 + g] = f * ej[j];   // lane-consecutive per j: conflict-free
  }

  float* orow = out + (size_t)m * 100;
  for (int p = lane; p < 100; p += 64) {
    const unsigned short* iv = &sinv[p * 16];
    float s2 = 0.f;
    #pragma unroll
    for (int i = 0; i < 16; i++) {
      int a = iv[i];
      s2 += sarc[wv][(a & 7) * 200 + (a >> 3)];
    }
    orow[p] = __logf(s2);
  }
}

extern "C" void kernel_launch(void* const* d_in, const int* in_sizes, int n_in,
                              void* d_out, int out_size, void* d_ws, size_t ws_size,
                              hipStream_t stream) {
  const float* phone_out = (const float*)d_in[0];
  const float* hs  = (const float*)d_in[1];
  const float* cw  = (const float*)d_in[2];  // (512,1,5,512): [out_ch][ki]
  const float* cb  = (const float*)d_in[3];
  const float* w1  = (const float*)d_in[4];
  const float* b1  = (const float*)d_in[5];
  const float* w2  = (const float*)d_in[6];
  const float* b2  = (const float*)d_in[7];
  const int* phn   = (const int*)d_in[8];
  const int* pal   = (const int*)d_in[9];
  float* out = (float*)d_out;

  // workspace layout (u16 units). Regions contiguous; gemm256's unclamped
  // K-overrun (<= 2 K-tiles) lands in the next region (all allocated).
  unsigned short* ws   = (unsigned short*)d_ws;
  unsigned short* cwT  = ws;                                    // 2560*512
  unsigned short* w1b  = cwT + (size_t)2560 * 512;              //  512*512
  unsigned short* w1cw = w1b + (size_t)512 * 512;               //  512*2560
  unsigned short* w2b  = w1cw + (size_t)512 * 2560;             // 1664*512 (1600 used)
  float*          bc   = (float*)(w2b + (size_t)1664 * 512);    //  512 f32
  unsigned short* inv  = (unsigned short*)(bc + 512);           // 1600 u16 (+pad)
  unsigned short* h2   = inv + 1664;                            // 32768*512
  unsigned short* X    = h2 + (size_t)32768 * 512;
  unsigned short* xpad = X;                                     // 32*1028*512
  unsigned short* Wm   = X;                                     // 32768*1600 (aliases dead xpad)

  k_prep<<<1811, 256, 0, stream>>>(w1, w2, cw, cb, b1, pal, w1b, w2b, cwT, bc, inv);
  k_pad_cast<<<8224, 256, 0, stream>>>(hs, xpad);

  // prep: w1cw[o][ki] = sum_j w1[o][j]*cw[j][ki]   (M=512, N=2560, K=512)
  k_gemm_bt<0><<<dim3(4, 20), 256, 0, stream>>>(w1b, cwT, nullptr, w1cw, 512, 2560, 128);
  // G1 = conv+FC1 folded: h2 = im2col(xpad) @ w1cw^T + bc  (M=32768, N=512, K=2560)
  k_gemm256<1, 2, 0><<<256, 512, 0, stream>>>(xpad, w1cw, bc, h2, 512, 2560);
  // G2 main: cols 0..1535, persistent 3-tile (256 blocks = 1/CU, m-panel fixed)
  k_gemm256<0, 6, 1><<<256, 512, 0, stream>>>(h2, w2b, b2, Wm, 1600, 512);
  // G2 tail: cols 1536..1599 via 128^2 kernel (B rows 1536..1663, 64 valid cols)
  k_gemm_bt<1><<<dim3(256, 1), 256, 0, stream>>>(
      h2, w2b + (size_t)1536 * 512, b2 + 1536, Wm + 1536, 512, 1600, 64);

  k_epilogue<<<8192, 256, 0, stream>>>(Wm, phone_out, phn, inv, out);
}

// Round 8
// 251.622 us; speedup vs baseline: 1.2694x; 1.2694x over previous
//
#include <hip/hip_runtime.h>
#include <hip/hip_bf16.h>

#define T_    1024
#define TP    1028   // T + 4 (pad 2 each side)

typedef __attribute__((ext_vector_type(8))) short short8;
typedef __attribute__((ext_vector_type(4))) float floatx4;

__device__ __forceinline__ unsigned short f2bf(float f) {
  union { float f; unsigned u; } x; x.f = f;
  unsigned r = x.u + 0x7FFFu + ((x.u >> 16) & 1u);
  return (unsigned short)(r >> 16);
}
__device__ __forceinline__ unsigned short f2bf_trunc(float f) {
  union { float f; unsigned u; } x; x.f = f;
  return (unsigned short)(x.u >> 16);
}
__device__ __forceinline__ float bf2f(unsigned short u) {
  union { unsigned u; float f; } x; x.u = ((unsigned)u) << 16;
  return x.f;
}

// ---------------- pad + cast hs_pad (B,T,512) f32 -> (B,T+4,512) bf16, zero borders
__global__ __launch_bounds__(256) void k_pad_cast(const float* __restrict__ hs,
                                                  unsigned short* __restrict__ xp) {
  size_t i = (size_t)blockIdx.x * 256 + threadIdx.x;
  size_t e = i * 8;
  int c = (int)(e & 511);
  size_t rb = e >> 9;
  int r = (int)(rb % TP);
  int b = (int)(rb / TP);
  int t = r - 2;
  short8 v;
  if (t >= 0 && t < T_) {
    const float* src = hs + (((size_t)b * T_ + t) << 9) + c;
    #pragma unroll
    for (int j = 0; j < 8; j++) v[j] = (short)f2bf(src[j]);
  } else {
    #pragma unroll
    for (int j = 0; j < 8; j++) v[j] = 0;
  }
  *(short8*)(xp + e) = v;
}

// ---------------- merged prep: w1 cast | w2 cast | conv_w transpose-cast |
// bias fold | inverse table. Partitioned by blockIdx.
__global__ __launch_bounds__(256) void k_prep(
    const float* __restrict__ w1, const float* __restrict__ w2,
    const float* __restrict__ cw, const float* __restrict__ cb,
    const float* __restrict__ b1, const int* __restrict__ pal,
    unsigned short* __restrict__ w1b, unsigned short* __restrict__ w2b,
    unsigned short* __restrict__ cwT, float* __restrict__ bc,
    unsigned short* __restrict__ inv) {
  __shared__ float tile[32][33];
  __shared__ int scnt[100];
  int b = blockIdx.x, tid = threadIdx.x;
  if (b < 128) {                     // w1 f32->bf16 (512*512)
    size_t e = ((size_t)b * 256 + tid) * 8;
    short8 v;
    #pragma unroll
    for (int j = 0; j < 8; j++) v[j] = (short)f2bf(w1[e + j]);
    *(short8*)(w1b + e) = v;
  } else if (b < 528) {              // w2 f32->bf16 (1600*512)
    size_t e = ((size_t)(b - 128) * 256 + tid) * 8;
    short8 v;
    #pragma unroll
    for (int j = 0; j < 8; j++) v[j] = (short)f2bf(w2[e + j]);
    *(short8*)(w2b + e) = v;
  } else if (b < 1808) {             // cw[j][ki] (512x2560) -> cwT[ki][j] bf16
    int bb = b - 528;
    int bx = bb % 80, by = bb / 80;
    int tx = tid & 31, ty = tid >> 5;
    #pragma unroll
    for (int dy = 0; dy < 4; dy++) {
      int j = by * 32 + ty + dy * 8;
      tile[ty + dy * 8][tx] = cw[(size_t)j * 2560 + bx * 32 + tx];
    }
    __syncthreads();
    #pragma unroll
    for (int dy = 0; dy < 4; dy++) {
      int ki = bx * 32 + ty + dy * 8;
      cwT[(size_t)ki * 512 + by * 32 + tx] = f2bf(tile[tx][ty + dy * 8]);
    }
  } else if (b < 1810) {             // bc[o] = b1[o] + sum_j w1[o][j]*cb[j]
    int o = (b - 1808) * 256 + tid;
    float s = b1[o];
    for (int j = 0; j < 512; j++) s += w1[(size_t)o * 512 + j] * cb[j];
    bc[o] = s;
  } else {                           // inv[p*16+slot] = arc
    if (tid < 100) scnt[tid] = 0;
    __syncthreads();
    for (int a = tid; a < 1600; a += 256) {
      int p = pal[a];
      int slot = atomicAdd(&scnt[p], 1);
      inv[p * 16 + slot] = (unsigned short)a;
    }
  }
}

// ---------------- 128^2 2-phase GEMM (prep GEMM + G2's 64-col tail)
template<int HAS_BIAS>
__global__ __launch_bounds__(256) void k_gemm_bt(
    const unsigned short* __restrict__ A, const unsigned short* __restrict__ Bt,
    const float* __restrict__ bias, unsigned short* __restrict__ C,
    int K, int ldc, int nvalid) {
  __shared__ unsigned short sA[128 * 64];
  __shared__ unsigned short sB[128 * 64];
  int tid  = threadIdx.x;
  int lane = tid & 63;
  int wv   = tid >> 6;
  int wr   = wv >> 1, wc = wv & 1;
  int m0 = blockIdx.x * 128;
  int n0 = blockIdx.y * 128;
  int l15  = lane & 15;
  int l_hi = lane >> 4;
  int srow = (wv << 3) + (lane >> 3);
  int scol = (((lane & 7) ^ ((lane >> 3) & 7)) << 3);
  int rkey = (l15 & 7) << 3;

  floatx4 acc[4][4];
  #pragma unroll
  for (int i = 0; i < 4; i++)
    #pragma unroll
    for (int j = 0; j < 4; j++) acc[i][j] = (floatx4){0.f, 0.f, 0.f, 0.f};

  for (int k0 = 0; k0 < K; k0 += 64) {
    __syncthreads();
    #pragma unroll
    for (int q = 0; q < 4; q++) {
      int r = (q << 5) + srow;
      const unsigned short* ga = A + (size_t)(m0 + r) * K + (k0 + scol);
      __builtin_amdgcn_global_load_lds(
          (const __attribute__((address_space(1))) void*)ga,
          (__attribute__((address_space(3))) void*)(sA + (q << 11) + (wv << 9)),
          16, 0, 0);
      const unsigned short* gb = Bt + (size_t)(n0 + r) * K + (k0 + scol);
      __builtin_amdgcn_global_load_lds(
          (const __attribute__((address_space(1))) void*)gb,
          (__attribute__((address_space(3))) void*)(sB + (q << 11) + (wv << 9)),
          16, 0, 0);
    }
    __syncthreads();
    #pragma unroll
    for (int ks = 0; ks < 2; ks++) {
      int col = ((ks << 5) + (l_hi << 3)) ^ rkey;
      short8 af[4], bfr[4];
      #pragma unroll
      for (int i = 0; i < 4; i++) {
        af[i]  = *(const short8*)(sA + (((wr << 6) + (i << 4) + l15) << 6) + col);
        bfr[i] = *(const short8*)(sB + (((wc << 6) + (i << 4) + l15) << 6) + col);
      }
      #pragma unroll
      for (int i = 0; i < 4; i++)
        #pragma unroll
        for (int j = 0; j < 4; j++)
          acc[i][j] = __builtin_amdgcn_mfma_f32_16x16x32_bf16(af[i], bfr[j], acc[i][j], 0, 0, 0);
    }
  }
  #pragma unroll
  for (int i = 0; i < 4; i++) {
    int row = m0 + (wr << 6) + (i << 4) + (l_hi << 2);
    #pragma unroll
    for (int j = 0; j < 4; j++) {
      int lcol = (wc << 6) + (j << 4) + l15;
      if (lcol < nvalid) {
        float bv = HAS_BIAS ? bias[n0 + lcol] : 0.f;
        #pragma unroll
        for (int jj = 0; jj < 4; jj++)
          C[(size_t)(row + jj) * ldc + n0 + lcol] = f2bf(acc[i][j][jj] + bv);
      }
    }
  }
}

// ---------------- 256^2 8-phase GEMM (T2+T3+T4+T5), C = A * Bt^T + bias
// R6-proven config: bijective XCD swizzle (logical = (bid%8)*(nwg/8) + bid/8),
// n-fast decode, ONE tile per block. (R7 lesson: persistent m-pinned blocks
// blow the per-XCD L2 -- 16 panels x 256KB + B > 4MB -- and re-fetch A 3x.)
// LDS: 8 slots [buf][op][half] of 128x64 bf16, XOR-swizzled; 8 waves (2Mx4N).
// STAGE has NO k clamp: overrun reads (<=2 K-tiles) land in allocated ws.
template<int CONV, int NY>
__global__ __launch_bounds__(512, 2) void k_gemm256(
    const unsigned short* __restrict__ A, const unsigned short* __restrict__ Bt,
    const float* __restrict__ bias, unsigned short* __restrict__ C,
    int N, int K) {
  __shared__ unsigned short lds[65536];   // 8 * 8192 u16
  const int tid = threadIdx.x;
  const int lane = tid & 63;
  const int w = tid >> 6;
  const int wm = w >> 2, wn = w & 3;
  const int l15 = lane & 15, l_hi = lane >> 4;
  const int rkey = (l15 & 7) << 3;
  const int bid = blockIdx.x;
  const int cpx = (int)gridDim.x >> 3;          // grid divisible by 8
  const int logical = (bid & 7) * cpx + (bid >> 3);
  const int m0 = (logical / NY) << 8, n0 = (logical % NY) << 8;
  const int nt = K >> 6;

  const int srow = tid >> 3;
  const int scol = (((tid & 7) ^ ((tid >> 3) & 7)) << 3);
  const unsigned short* abase;
  size_t astr;
  if (CONV) {
    int m = m0 + srow;                 // block never crosses a b-boundary (256 | 1024)
    int b = m >> 10, t = m & 1023;
    abase = A + (((size_t)b * TP + t) << 9) + scol;
    astr = 512;                        // im2col: +1 row = +512 elems
  } else {
    abase = A + (size_t)(m0 + srow) * K + scol;
    astr = (size_t)K;
  }
  const unsigned short* bbase = Bt + (size_t)(n0 + srow) * K + scol;
  const size_t bstr = (size_t)K;

  #define SLOT(buf, op, h) ((((((buf) << 1) | (op)) << 1) | (h)) * 8192)

  auto STAGE = [&](int buf, int op, int h, int kt) {
    const unsigned short* g0 = (op ? bbase : abase)
        + (size_t)(h * 128) * (op ? bstr : astr) + (size_t)kt * 64;
    unsigned short* d = lds + SLOT(buf, op, h) + w * 512;
    __builtin_amdgcn_global_load_lds(
        (const __attribute__((address_space(1))) void*)g0,
        (__attribute__((address_space(3))) void*)d, 16, 0, 0);
    __builtin_amdgcn_global_load_lds(
        (const __attribute__((address_space(1))) void*)(g0 + (size_t)64 * (op ? bstr : astr)),
        (__attribute__((address_space(3))) void*)(d + 4096), 16, 0, 0);
  };

  auto RDA = [&](short8* dst, int buf, int rh) {        // 4 row-frags x 2 ks
    const unsigned short* s = lds + SLOT(buf, 0, wm);
    #pragma unroll
    for (int i = 0; i < 4; i++) {
      int row = (((rh << 2) + i) << 4) + l15;
      #pragma unroll
      for (int ks = 0; ks < 2; ks++) {
        int col = (((ks << 5) + (l_hi << 3)) ^ rkey);
        dst[i * 2 + ks] = *(const short8*)(s + (row << 6) + col);
      }
    }
  };
  auto RDB = [&](short8* dst, int buf, int jh) {        // 2 col-frags x 2 ks
    const unsigned short* s = lds + SLOT(buf, 1, (wn >> 1));
    #pragma unroll
    for (int j = 0; j < 2; j++) {
      int row = ((wn & 1) << 6) + (((jh << 1) + j) << 4) + l15;
      #pragma unroll
      for (int ks = 0; ks < 2; ks++) {
        int col = (((ks << 5) + (l_hi << 3)) ^ rkey);
        dst[j * 2 + ks] = *(const short8*)(s + (row << 6) + col);
      }
    }
  };

  floatx4 acc[8][4];
  #pragma unroll
  for (int i = 0; i < 8; i++)
    #pragma unroll
    for (int j = 0; j < 4; j++) acc[i][j] = (floatx4){0.f, 0.f, 0.f, 0.f};

  #define MMQ(ar, br, rh, ch)                                                  \
    __builtin_amdgcn_s_setprio(1);                                             \
    _Pragma("unroll")                                                          \
    for (int i = 0; i < 4; i++)                                                \
      _Pragma("unroll")                                                        \
      for (int j = 0; j < 2; j++)                                              \
        _Pragma("unroll")                                                      \
        for (int ks = 0; ks < 2; ks++)                                         \
          acc[((rh) << 2) + i][((ch) << 1) + j] =                              \
              __builtin_amdgcn_mfma_f32_16x16x32_bf16(                         \
                  ar[i * 2 + ks], br[j * 2 + ks],                              \
                  acc[((rh) << 2) + i][((ch) << 1) + j], 0, 0, 0);             \
    __builtin_amdgcn_s_setprio(0);

  // prologue: T0 fully (buf0), T1.B (buf1)
  STAGE(0, 1, 0, 0); STAGE(0, 1, 1, 0); STAGE(0, 0, 0, 0); STAGE(0, 0, 1, 0);
  STAGE(1, 1, 0, 1); STAGE(1, 1, 1, 1);
  asm volatile("s_waitcnt vmcnt(4)" ::: "memory");
  __builtin_amdgcn_s_barrier();

  short8 aR[8], bR0[4], bR1[4];
  const int niter = nt >> 1;
  for (int it = 0; it < niter; ++it) {
    const int t0 = it << 1;
    // p1: tile t0 q(0,0)
    RDA(aR, 0, 0); RDB(bR0, 0, 0);
    STAGE(1, 0, 0, t0 + 1);
    __builtin_amdgcn_s_barrier();
    MMQ(aR, bR0, 0, 0);
    __builtin_amdgcn_s_barrier();
    // p2: q(0,1)
    RDB(bR1, 0, 1);
    STAGE(1, 0, 1, t0 + 1);
    __builtin_amdgcn_s_barrier();
    MMQ(aR, bR1, 0, 1);
    __builtin_amdgcn_s_barrier();
    // p3: q(1,0)
    RDA(aR, 0, 1);
    STAGE(0, 1, 0, t0 + 2);
    __builtin_amdgcn_s_barrier();
    MMQ(aR, bR0, 1, 0);
    __builtin_amdgcn_s_barrier();
    // p4: q(1,1)  [+ tile-boundary wait]
    STAGE(0, 1, 1, t0 + 2);
    __builtin_amdgcn_s_barrier();
    MMQ(aR, bR1, 1, 1);
    asm volatile("s_waitcnt vmcnt(4)" ::: "memory");
    __builtin_amdgcn_s_barrier();
    // p5: tile t0+1 q(0,0)
    RDA(aR, 1, 0); RDB(bR0, 1, 0);
    STAGE(0, 0, 0, t0 + 2);
    __builtin_amdgcn_s_barrier();
    MMQ(aR, bR0, 0, 0);
    __builtin_amdgcn_s_barrier();
    // p6: q(0,1)
    RDB(bR1, 1, 1);
    STAGE(0, 0, 1, t0 + 2);
    __builtin_amdgcn_s_barrier();
    MMQ(aR, bR1, 0, 1);
    __builtin_amdgcn_s_barrier();
    // p7: q(1,0)
    RDA(aR, 1, 1);
    STAGE(1, 1, 0, t0 + 3);
    __builtin_amdgcn_s_barrier();
    MMQ(aR, bR0, 1, 0);
    __builtin_amdgcn_s_barrier();
    // p8: q(1,1)  [+ tile-boundary wait]
    STAGE(1, 1, 1, t0 + 3);
    __builtin_amdgcn_s_barrier();
    MMQ(aR, bR1, 1, 1);
    asm volatile("s_waitcnt vmcnt(4)" ::: "memory");
    __builtin_amdgcn_s_barrier();
  }

  #pragma unroll
  for (int i = 0; i < 8; i++) {
    int row = m0 + (wm << 7) + (i << 4) + (l_hi << 2);
    #pragma unroll
    for (int j = 0; j < 4; j++) {
      int col = n0 + (wn << 6) + (j << 4) + l15;
      float bv = bias[col];
      #pragma unroll
      for (int jj = 0; jj < 4; jj++)
        C[(size_t)(row + jj) * N + col] = f2bf(acc[i][j][jj] + bv);
    }
  }
  #undef SLOT
  #undef MMQ
}

// ---------------- fused epilogue (gather form, no atomics)
// bf16 sarc: LDS 33 -> 19.6 KB/block => 8 blocks/CU (32 waves/CU resident,
// 2x latency hiding for the Wm stream). Truncated bf16 (values in [0,1]):
// rel err ~0.4% -> log abs err ~0.004, far under the 0.126 threshold.
// Group-uniform phone labels: one selp lookup per group.
__global__ __launch_bounds__(256) void k_epilogue(
    const unsigned short* __restrict__ Wm, const float* __restrict__ po,
    const int* __restrict__ phn, const unsigned short* __restrict__ inv_g,
    float* __restrict__ out) {
  __shared__ unsigned short sphn[200];     // per-group phone (arc 8g)
  __shared__ unsigned short sinv[1600];
  __shared__ float selp[4][200];
  __shared__ unsigned short sarc[4][1600]; // bf16, layout [j][200]: j*200+g
  int tid = threadIdx.x;
  int lane = tid & 63;
  int wv = tid >> 6;
  for (int i = tid; i < 1600; i += 256) sinv[i] = inv_g[i];
  if (tid < 200) sphn[tid] = (unsigned short)phn[tid << 3];
  __syncthreads();
  int m = blockIdx.x * 4 + wv;

  const float* porow = po + (size_t)m * 200;
  float v[4];
  float mx = -1e30f;
  #pragma unroll
  for (int gi = 0; gi < 4; gi++) {
    int g = lane + gi * 64;
    v[gi] = (g < 200) ? porow[g] : -1e30f;
    mx = fmaxf(mx, v[gi]);
  }
  #pragma unroll
  for (int o = 32; o >= 1; o >>= 1) mx = fmaxf(mx, __shfl_xor(mx, o));
  float ev[4];
  float s = 0.f;
  #pragma unroll
  for (int gi = 0; gi < 4; gi++) {
    int g = lane + gi * 64;
    if (g < 200) { ev[gi] = __expf(v[gi] - mx); s += ev[gi]; }
  }
  #pragma unroll
  for (int o = 32; o >= 1; o >>= 1) s += __shfl_xor(s, o);
  float rs = __builtin_amdgcn_rcpf(s);
  #pragma unroll
  for (int gi = 0; gi < 4; gi++) {
    int g = lane + gi * 64;
    if (g < 200) selp[wv][g] = ev[gi] * rs;
  }

  const unsigned short* wrow = Wm + (size_t)m * 1600;
  for (int g = lane; g < 200; g += 64) {
    short8 wb = *(const short8*)(wrow + g * 8);
    float w[8];
    #pragma unroll
    for (int j = 0; j < 8; j++) w[j] = bf2f((unsigned short)wb[j]);
    float gm = w[0];
    #pragma unroll
    for (int j = 1; j < 8; j++) gm = fmaxf(gm, w[j]);
    float ej[8];
    float se = 0.f;
    #pragma unroll
    for (int j = 0; j < 8; j++) { ej[j] = __expf(w[j] - gm); se += ej[j]; }
    float f = selp[wv][sphn[g]] * __builtin_amdgcn_rcpf(se);
    #pragma unroll
    for (int j = 0; j < 8; j++)
      sarc[wv][j * 200 + g] = f2bf_trunc(f * ej[j]);  // lane-consecutive per j
  }

  float* orow = out + (size_t)m * 100;
  for (int p = lane; p < 100; p += 64) {
    const unsigned short* iv = &sinv[p * 16];
    float s2 = 0.f;
    #pragma unroll
    for (int i = 0; i < 16; i++) {
      int a = iv[i];
      s2 += bf2f(sarc[wv][(a & 7) * 200 + (a >> 3)]);
    }
    orow[p] = __logf(s2);
  }
}

extern "C" void kernel_launch(void* const* d_in, const int* in_sizes, int n_in,
                              void* d_out, int out_size, void* d_ws, size_t ws_size,
                              hipStream_t stream) {
  const float* phone_out = (const float*)d_in[0];
  const float* hs  = (const float*)d_in[1];
  const float* cw  = (const float*)d_in[2];  // (512,1,5,512): [out_ch][ki]
  const float* cb  = (const float*)d_in[3];
  const float* w1  = (const float*)d_in[4];
  const float* b1  = (const float*)d_in[5];
  const float* w2  = (const float*)d_in[6];
  const float* b2  = (const float*)d_in[7];
  const int* phn   = (const int*)d_in[8];
  const int* pal   = (const int*)d_in[9];
  float* out = (float*)d_out;

  // workspace layout (u16 units). Regions contiguous; gemm256's unclamped
  // K-overrun (<= 2 K-tiles) lands in the next region (all allocated).
  unsigned short* ws   = (unsigned short*)d_ws;
  unsigned short* cwT  = ws;                                    // 2560*512
  unsigned short* w1b  = cwT + (size_t)2560 * 512;              //  512*512
  unsigned short* w1cw = w1b + (size_t)512 * 512;               //  512*2560
  unsigned short* w2b  = w1cw + (size_t)512 * 2560;             // 1664*512 (1600 used)
  float*          bc   = (float*)(w2b + (size_t)1664 * 512);    //  512 f32
  unsigned short* inv  = (unsigned short*)(bc + 512);           // 1600 u16 (+pad)
  unsigned short* h2   = inv + 1664;                            // 32768*512
  unsigned short* X    = h2 + (size_t)32768 * 512;
  unsigned short* xpad = X;                                     // 32*1028*512
  unsigned short* Wm   = X;                                     // 32768*1600 (aliases dead xpad)

  k_prep<<<1811, 256, 0, stream>>>(w1, w2, cw, cb, b1, pal, w1b, w2b, cwT, bc, inv);
  k_pad_cast<<<8224, 256, 0, stream>>>(hs, xpad);

  // prep: w1cw[o][ki] = sum_j w1[o][j]*cw[j][ki]   (M=512, N=2560, K=512)
  k_gemm_bt<0><<<dim3(4, 20), 256, 0, stream>>>(w1b, cwT, nullptr, w1cw, 512, 2560, 128);
  // G1 = conv+FC1 folded: h2 = im2col(xpad) @ w1cw^T + bc  (M=32768, N=512, K=2560)
  k_gemm256<1, 2><<<256, 512, 0, stream>>>(xpad, w1cw, bc, h2, 512, 2560);
  // G2 main: cols 0..1535 (exact cover, 768 blocks = 3 full rounds)
  k_gemm256<0, 6><<<768, 512, 0, stream>>>(h2, w2b, b2, Wm, 1600, 512);
  // G2 tail: cols 1536..1599 via 128^2 kernel (B rows 1536..1663, 64 valid cols)
  k_gemm_bt<1><<<dim3(256, 1), 256, 0, stream>>>(
      h2, w2b + (size_t)1536 * 512, b2 + 1536, Wm + 1536, 512, 1600, 64);

  k_epilogue<<<8192, 256, 0, stream>>>(Wm, phone_out, phn, inv, out);
}

// Round 9
// 237.517 us; speedup vs baseline: 1.3448x; 1.0594x over previous
//
#include <hip/hip_runtime.h>
#include <hip/hip_bf16.h>

#define T_    1024
#define TP    1028   // T + 4 (pad 2 each side)

typedef __attribute__((ext_vector_type(8))) short short8;
typedef __attribute__((ext_vector_type(4))) float floatx4;

__device__ __forceinline__ unsigned short f2bf(float f) {
  union { float f; unsigned u; } x; x.f = f;
  unsigned r = x.u + 0x7FFFu + ((x.u >> 16) & 1u);
  return (unsigned short)(r >> 16);
}
__device__ __forceinline__ unsigned short f2bf_trunc(float f) {
  union { float f; unsigned u; } x; x.f = f;
  return (unsigned short)(x.u >> 16);
}
__device__ __forceinline__ float bf2f(unsigned short u) {
  union { unsigned u; float f; } x; x.u = ((unsigned)u) << 16;
  return x.f;
}

// ---------------- pad + cast hs_pad (B,T,512) f32 -> (B,T+4,512) bf16.
// 2-D grid (257 x 32): batch = blockIdx.y, 257*256*8 == TP*512 exactly --
// all addressing is shift/mask, no div/mod by 1028.
__global__ __launch_bounds__(256) void k_pad_cast(const float* __restrict__ hs,
                                                  unsigned short* __restrict__ xp) {
  int b = blockIdx.y;
  size_t e = ((size_t)blockIdx.x * 256 + threadIdx.x) * 8;   // < TP*512
  int r = (int)(e >> 9);
  int c = (int)(e & 511);
  int t = r - 2;
  short8 v;
  if (t >= 0 && t < T_) {
    const float* src = hs + (((size_t)b * T_ + t) << 9) + c;
    #pragma unroll
    for (int j = 0; j < 8; j++) v[j] = (short)f2bf(src[j]);
  } else {
    #pragma unroll
    for (int j = 0; j < 8; j++) v[j] = 0;
  }
  *(short8*)(xp + (((size_t)b * TP) << 9) + e) = v;
}

// ---------------- merged prep: w1 cast | w2 cast | conv_w transpose-cast |
// bias fold | inverse table. Partitioned by blockIdx.
__global__ __launch_bounds__(256) void k_prep(
    const float* __restrict__ w1, const float* __restrict__ w2,
    const float* __restrict__ cw, const float* __restrict__ cb,
    const float* __restrict__ b1, const int* __restrict__ pal,
    unsigned short* __restrict__ w1b, unsigned short* __restrict__ w2b,
    unsigned short* __restrict__ cwT, float* __restrict__ bc,
    unsigned short* __restrict__ inv) {
  __shared__ float tile[32][33];
  __shared__ int scnt[100];
  int b = blockIdx.x, tid = threadIdx.x;
  if (b < 128) {                     // w1 f32->bf16 (512*512)
    size_t e = ((size_t)b * 256 + tid) * 8;
    short8 v;
    #pragma unroll
    for (int j = 0; j < 8; j++) v[j] = (short)f2bf(w1[e + j]);
    *(short8*)(w1b + e) = v;
  } else if (b < 528) {              // w2 f32->bf16 (1600*512)
    size_t e = ((size_t)(b - 128) * 256 + tid) * 8;
    short8 v;
    #pragma unroll
    for (int j = 0; j < 8; j++) v[j] = (short)f2bf(w2[e + j]);
    *(short8*)(w2b + e) = v;
  } else if (b < 1808) {             // cw[j][ki] (512x2560) -> cwT[ki][j] bf16
    int bb = b - 528;
    int bx = bb % 80, by = bb / 80;
    int tx = tid & 31, ty = tid >> 5;
    #pragma unroll
    for (int dy = 0; dy < 4; dy++) {
      int j = by * 32 + ty + dy * 8;
      tile[ty + dy * 8][tx] = cw[(size_t)j * 2560 + bx * 32 + tx];
    }
    __syncthreads();
    #pragma unroll
    for (int dy = 0; dy < 4; dy++) {
      int ki = bx * 32 + ty + dy * 8;
      cwT[(size_t)ki * 512 + by * 32 + tx] = f2bf(tile[tx][ty + dy * 8]);
    }
  } else if (b < 1810) {             // bc[o] = b1[o] + sum_j w1[o][j]*cb[j]
    int o = (b - 1808) * 256 + tid;
    float s = b1[o];
    for (int j = 0; j < 512; j++) s += w1[(size_t)o * 512 + j] * cb[j];
    bc[o] = s;
  } else {                           // inv[p*16+slot] = arc
    if (tid < 100) scnt[tid] = 0;
    __syncthreads();
    for (int a = tid; a < 1600; a += 256) {
      int p = pal[a];
      int slot = atomicAdd(&scnt[p], 1);
      inv[p * 16 + slot] = (unsigned short)a;
    }
  }
}

// ---------------- 128^2 2-phase GEMM (prep GEMM + G2's 64-col tail)
template<int HAS_BIAS>
__global__ __launch_bounds__(256) void k_gemm_bt(
    const unsigned short* __restrict__ A, const unsigned short* __restrict__ Bt,
    const float* __restrict__ bias, unsigned short* __restrict__ C,
    int K, int ldc, int nvalid) {
  __shared__ unsigned short sA[128 * 64];
  __shared__ unsigned short sB[128 * 64];
  int tid  = threadIdx.x;
  int lane = tid & 63;
  int wv   = tid >> 6;
  int wr   = wv >> 1, wc = wv & 1;
  int m0 = blockIdx.x * 128;
  int n0 = blockIdx.y * 128;
  int l15  = lane & 15;
  int l_hi = lane >> 4;
  int srow = (wv << 3) + (lane >> 3);
  int scol = (((lane & 7) ^ ((lane >> 3) & 7)) << 3);
  int rkey = (l15 & 7) << 3;

  floatx4 acc[4][4];
  #pragma unroll
  for (int i = 0; i < 4; i++)
    #pragma unroll
    for (int j = 0; j < 4; j++) acc[i][j] = (floatx4){0.f, 0.f, 0.f, 0.f};

  for (int k0 = 0; k0 < K; k0 += 64) {
    __syncthreads();
    #pragma unroll
    for (int q = 0; q < 4; q++) {
      int r = (q << 5) + srow;
      const unsigned short* ga = A + (size_t)(m0 + r) * K + (k0 + scol);
      __builtin_amdgcn_global_load_lds(
          (const __attribute__((address_space(1))) void*)ga,
          (__attribute__((address_space(3))) void*)(sA + (q << 11) + (wv << 9)),
          16, 0, 0);
      const unsigned short* gb = Bt + (size_t)(n0 + r) * K + (k0 + scol);
      __builtin_amdgcn_global_load_lds(
          (const __attribute__((address_space(1))) void*)gb,
          (__attribute__((address_space(3))) void*)(sB + (q << 11) + (wv << 9)),
          16, 0, 0);
    }
    __syncthreads();
    #pragma unroll
    for (int ks = 0; ks < 2; ks++) {
      int col = ((ks << 5) + (l_hi << 3)) ^ rkey;
      short8 af[4], bfr[4];
      #pragma unroll
      for (int i = 0; i < 4; i++) {
        af[i]  = *(const short8*)(sA + (((wr << 6) + (i << 4) + l15) << 6) + col);
        bfr[i] = *(const short8*)(sB + (((wc << 6) + (i << 4) + l15) << 6) + col);
      }
      #pragma unroll
      for (int i = 0; i < 4; i++)
        #pragma unroll
        for (int j = 0; j < 4; j++)
          acc[i][j] = __builtin_amdgcn_mfma_f32_16x16x32_bf16(af[i], bfr[j], acc[i][j], 0, 0, 0);
    }
  }
  #pragma unroll
  for (int i = 0; i < 4; i++) {
    int row = m0 + (wr << 6) + (i << 4) + (l_hi << 2);
    #pragma unroll
    for (int j = 0; j < 4; j++) {
      int lcol = (wc << 6) + (j << 4) + l15;
      if (lcol < nvalid) {
        float bv = HAS_BIAS ? bias[n0 + lcol] : 0.f;
        #pragma unroll
        for (int jj = 0; jj < 4; jj++)
          C[(size_t)(row + jj) * ldc + n0 + lcol] = f2bf(acc[i][j][jj] + bv);
      }
    }
  }
}

// ---------------- 256^2 8-phase GEMM (T2+T3+T4+T5), C = A * Bt^T + bias
// R6-proven config: bijective XCD swizzle, n-fast decode, ONE tile per block.
// STAGE predicated on kt < nt: trailing overrun stages are SKIPPED (for K=512
// they were 6/22 = 27% of staging volume, and the drain's vmcnt waited on
// them). Skipping only reduces outstanding vmem ops, so every counted
// vmcnt(4) becomes a strictly stronger wait -- ledger unchanged.
// LDS: 8 slots [buf][op][half] of 128x64 bf16, XOR-swizzled; 8 waves (2Mx4N).
template<int CONV, int NY>
__global__ __launch_bounds__(512, 2) void k_gemm256(
    const unsigned short* __restrict__ A, const unsigned short* __restrict__ Bt,
    const float* __restrict__ bias, unsigned short* __restrict__ C,
    int N, int K) {
  __shared__ unsigned short lds[65536];   // 8 * 8192 u16
  const int tid = threadIdx.x;
  const int lane = tid & 63;
  const int w = tid >> 6;
  const int wm = w >> 2, wn = w & 3;
  const int l15 = lane & 15, l_hi = lane >> 4;
  const int rkey = (l15 & 7) << 3;
  const int bid = blockIdx.x;
  const int cpx = (int)gridDim.x >> 3;          // grid divisible by 8
  const int logical = (bid & 7) * cpx + (bid >> 3);
  const int m0 = (logical / NY) << 8, n0 = (logical % NY) << 8;
  const int nt = K >> 6;

  const int srow = tid >> 3;
  const int scol = (((tid & 7) ^ ((tid >> 3) & 7)) << 3);
  const unsigned short* abase;
  size_t astr;
  if (CONV) {
    int m = m0 + srow;                 // block never crosses a b-boundary (256 | 1024)
    int b = m >> 10, t = m & 1023;
    abase = A + (((size_t)b * TP + t) << 9) + scol;
    astr = 512;                        // im2col: +1 row = +512 elems
  } else {
    abase = A + (size_t)(m0 + srow) * K + scol;
    astr = (size_t)K;
  }
  const unsigned short* bbase = Bt + (size_t)(n0 + srow) * K + scol;
  const size_t bstr = (size_t)K;

  #define SLOT(buf, op, h) ((((((buf) << 1) | (op)) << 1) | (h)) * 8192)

  auto STAGE = [&](int buf, int op, int h, int kt) {
    if (kt >= nt) return;            // skip overrun (uniform scalar branch)
    const unsigned short* g0 = (op ? bbase : abase)
        + (size_t)(h * 128) * (op ? bstr : astr) + (size_t)kt * 64;
    unsigned short* d = lds + SLOT(buf, op, h) + w * 512;
    __builtin_amdgcn_global_load_lds(
        (const __attribute__((address_space(1))) void*)g0,
        (__attribute__((address_space(3))) void*)d, 16, 0, 0);
    __builtin_amdgcn_global_load_lds(
        (const __attribute__((address_space(1))) void*)(g0 + (size_t)64 * (op ? bstr : astr)),
        (__attribute__((address_space(3))) void*)(d + 4096), 16, 0, 0);
  };

  auto RDA = [&](short8* dst, int buf, int rh) {        // 4 row-frags x 2 ks
    const unsigned short* s = lds + SLOT(buf, 0, wm);
    #pragma unroll
    for (int i = 0; i < 4; i++) {
      int row = (((rh << 2) + i) << 4) + l15;
      #pragma unroll
      for (int ks = 0; ks < 2; ks++) {
        int col = (((ks << 5) + (l_hi << 3)) ^ rkey);
        dst[i * 2 + ks] = *(const short8*)(s + (row << 6) + col);
      }
    }
  };
  auto RDB = [&](short8* dst, int buf, int jh) {        // 2 col-frags x 2 ks
    const unsigned short* s = lds + SLOT(buf, 1, (wn >> 1));
    #pragma unroll
    for (int j = 0; j < 2; j++) {
      int row = ((wn & 1) << 6) + (((jh << 1) + j) << 4) + l15;
      #pragma unroll
      for (int ks = 0; ks < 2; ks++) {
        int col = (((ks << 5) + (l_hi << 3)) ^ rkey);
        dst[j * 2 + ks] = *(const short8*)(s + (row << 6) + col);
      }
    }
  };

  floatx4 acc[8][4];
  #pragma unroll
  for (int i = 0; i < 8; i++)
    #pragma unroll
    for (int j = 0; j < 4; j++) acc[i][j] = (floatx4){0.f, 0.f, 0.f, 0.f};

  #define MMQ(ar, br, rh, ch)                                                  \
    __builtin_amdgcn_s_setprio(1);                                             \
    _Pragma("unroll")                                                          \
    for (int i = 0; i < 4; i++)                                                \
      _Pragma("unroll")                                                        \
      for (int j = 0; j < 2; j++)                                              \
        _Pragma("unroll")                                                      \
        for (int ks = 0; ks < 2; ks++)                                         \
          acc[((rh) << 2) + i][((ch) << 1) + j] =                              \
              __builtin_amdgcn_mfma_f32_16x16x32_bf16(                         \
                  ar[i * 2 + ks], br[j * 2 + ks],                              \
                  acc[((rh) << 2) + i][((ch) << 1) + j], 0, 0, 0);             \
    __builtin_amdgcn_s_setprio(0);

  // prologue: T0 fully (buf0), T1.B (buf1)
  STAGE(0, 1, 0, 0); STAGE(0, 1, 1, 0); STAGE(0, 0, 0, 0); STAGE(0, 0, 1, 0);
  STAGE(1, 1, 0, 1); STAGE(1, 1, 1, 1);
  asm volatile("s_waitcnt vmcnt(4)" ::: "memory");
  __builtin_amdgcn_s_barrier();

  short8 aR[8], bR0[4], bR1[4];
  const int niter = nt >> 1;
  for (int it = 0; it < niter; ++it) {
    const int t0 = it << 1;
    // p1: tile t0 q(0,0)
    RDA(aR, 0, 0); RDB(bR0, 0, 0);
    STAGE(1, 0, 0, t0 + 1);
    __builtin_amdgcn_s_barrier();
    MMQ(aR, bR0, 0, 0);
    __builtin_amdgcn_s_barrier();
    // p2: q(0,1)
    RDB(bR1, 0, 1);
    STAGE(1, 0, 1, t0 + 1);
    __builtin_amdgcn_s_barrier();
    MMQ(aR, bR1, 0, 1);
    __builtin_amdgcn_s_barrier();
    // p3: q(1,0)
    RDA(aR, 0, 1);
    STAGE(0, 1, 0, t0 + 2);
    __builtin_amdgcn_s_barrier();
    MMQ(aR, bR0, 1, 0);
    __builtin_amdgcn_s_barrier();
    // p4: q(1,1)  [+ tile-boundary wait]
    STAGE(0, 1, 1, t0 + 2);
    __builtin_amdgcn_s_barrier();
    MMQ(aR, bR1, 1, 1);
    asm volatile("s_waitcnt vmcnt(4)" ::: "memory");
    __builtin_amdgcn_s_barrier();
    // p5: tile t0+1 q(0,0)
    RDA(aR, 1, 0); RDB(bR0, 1, 0);
    STAGE(0, 0, 0, t0 + 2);
    __builtin_amdgcn_s_barrier();
    MMQ(aR, bR0, 0, 0);
    __builtin_amdgcn_s_barrier();
    // p6: q(0,1)
    RDB(bR1, 1, 1);
    STAGE(0, 0, 1, t0 + 2);
    __builtin_amdgcn_s_barrier();
    MMQ(aR, bR1, 0, 1);
    __builtin_amdgcn_s_barrier();
    // p7: q(1,0)
    RDA(aR, 1, 1);
    STAGE(1, 1, 0, t0 + 3);
    __builtin_amdgcn_s_barrier();
    MMQ(aR, bR0, 1, 0);
    __builtin_amdgcn_s_barrier();
    // p8: q(1,1)  [+ tile-boundary wait]
    STAGE(1, 1, 1, t0 + 3);
    __builtin_amdgcn_s_barrier();
    MMQ(aR, bR1, 1, 1);
    asm volatile("s_waitcnt vmcnt(4)" ::: "memory");
    __builtin_amdgcn_s_barrier();
  }

  #pragma unroll
  for (int i = 0; i < 8; i++) {
    int row = m0 + (wm << 7) + (i << 4) + (l_hi << 2);
    #pragma unroll
    for (int j = 0; j < 4; j++) {
      int col = n0 + (wn << 6) + (j << 4) + l15;
      float bv = bias[col];
      #pragma unroll
      for (int jj = 0; jj < 4; jj++)
        C[(size_t)(row + jj) * N + col] = f2bf(acc[i][j][jj] + bv);
    }
  }
  #undef SLOT
  #undef MMQ
}

// ---------------- fused epilogue (gather form, no atomics)
// bf16 sarc => 19.6 KB LDS/block => 8 blocks/CU resident.
__global__ __launch_bounds__(256) void k_epilogue(
    const unsigned short* __restrict__ Wm, const float* __restrict__ po,
    const int* __restrict__ phn, const unsigned short* __restrict__ inv_g,
    float* __restrict__ out) {
  __shared__ unsigned short sphn[200];     // per-group phone (arc 8g)
  __shared__ unsigned short sinv[1600];
  __shared__ float selp[4][200];
  __shared__ unsigned short sarc[4][1600]; // bf16, layout [j][200]: j*200+g
  int tid = threadIdx.x;
  int lane = tid & 63;
  int wv = tid >> 6;
  for (int i = tid; i < 1600; i += 256) sinv[i] = inv_g[i];
  if (tid < 200) sphn[tid] = (unsigned short)phn[tid << 3];
  __syncthreads();
  int m = blockIdx.x * 4 + wv;

  const float* porow = po + (size_t)m * 200;
  float v[4];
  float mx = -1e30f;
  #pragma unroll
  for (int gi = 0; gi < 4; gi++) {
    int g = lane + gi * 64;
    v[gi] = (g < 200) ? porow[g] : -1e30f;
    mx = fmaxf(mx, v[gi]);
  }
  #pragma unroll
  for (int o = 32; o >= 1; o >>= 1) mx = fmaxf(mx, __shfl_xor(mx, o));
  float ev[4];
  float s = 0.f;
  #pragma unroll
  for (int gi = 0; gi < 4; gi++) {
    int g = lane + gi * 64;
    if (g < 200) { ev[gi] = __expf(v[gi] - mx); s += ev[gi]; }
  }
  #pragma unroll
  for (int o = 32; o >= 1; o >>= 1) s += __shfl_xor(s, o);
  float rs = __builtin_amdgcn_rcpf(s);
  #pragma unroll
  for (int gi = 0; gi < 4; gi++) {
    int g = lane + gi * 64;
    if (g < 200) selp[wv][g] = ev[gi] * rs;
  }

  const unsigned short* wrow = Wm + (size_t)m * 1600;
  for (int g = lane; g < 200; g += 64) {
    short8 wb = *(const short8*)(wrow + g * 8);
    float w[8];
    #pragma unroll
    for (int j = 0; j < 8; j++) w[j] = bf2f((unsigned short)wb[j]);
    float gm = w[0];
    #pragma unroll
    for (int j = 1; j < 8; j++) gm = fmaxf(gm, w[j]);
    float ej[8];
    float se = 0.f;
    #pragma unroll
    for (int j = 0; j < 8; j++) { ej[j] = __expf(w[j] - gm); se += ej[j]; }
    float f = selp[wv][sphn[g]] * __builtin_amdgcn_rcpf(se);
    #pragma unroll
    for (int j = 0; j < 8; j++)
      sarc[wv][j * 200 + g] = f2bf_trunc(f * ej[j]);  // lane-consecutive per j
  }

  float* orow = out + (size_t)m * 100;
  for (int p = lane; p < 100; p += 64) {
    const unsigned short* iv = &sinv[p * 16];
    float s2 = 0.f;
    #pragma unroll
    for (int i = 0; i < 16; i++) {
      int a = iv[i];
      s2 += bf2f(sarc[wv][(a & 7) * 200 + (a >> 3)]);
    }
    orow[p] = __logf(s2);
  }
}

extern "C" void kernel_launch(void* const* d_in, const int* in_sizes, int n_in,
                              void* d_out, int out_size, void* d_ws, size_t ws_size,
                              hipStream_t stream) {
  const float* phone_out = (const float*)d_in[0];
  const float* hs  = (const float*)d_in[1];
  const float* cw  = (const float*)d_in[2];  // (512,1,5,512): [out_ch][ki]
  const float* cb  = (const float*)d_in[3];
  const float* w1  = (const float*)d_in[4];
  const float* b1  = (const float*)d_in[5];
  const float* w2  = (const float*)d_in[6];
  const float* b2  = (const float*)d_in[7];
  const int* phn   = (const int*)d_in[8];
  const int* pal   = (const int*)d_in[9];
  float* out = (float*)d_out;

  // workspace layout (u16 units). Regions contiguous.
  unsigned short* ws   = (unsigned short*)d_ws;
  unsigned short* cwT  = ws;                                    // 2560*512
  unsigned short* w1b  = cwT + (size_t)2560 * 512;              //  512*512
  unsigned short* w1cw = w1b + (size_t)512 * 512;               //  512*2560
  unsigned short* w2b  = w1cw + (size_t)512 * 2560;             // 1664*512 (1600 used)
  float*          bc   = (float*)(w2b + (size_t)1664 * 512);    //  512 f32
  unsigned short* inv  = (unsigned short*)(bc + 512);           // 1600 u16 (+pad)
  unsigned short* h2   = inv + 1664;                            // 32768*512
  unsigned short* X    = h2 + (size_t)32768 * 512;
  unsigned short* xpad = X;                                     // 32*1028*512
  unsigned short* Wm   = X;                                     // 32768*1600 (aliases dead xpad)

  k_prep<<<1811, 256, 0, stream>>>(w1, w2, cw, cb, b1, pal, w1b, w2b, cwT, bc, inv);
  k_pad_cast<<<dim3(257, 32), 256, 0, stream>>>(hs, xpad);

  // prep: w1cw[o][ki] = sum_j w1[o][j]*cw[j][ki]   (M=512, N=2560, K=512)
  k_gemm_bt<0><<<dim3(4, 20), 256, 0, stream>>>(w1b, cwT, nullptr, w1cw, 512, 2560, 128);
  // G1 = conv+FC1 folded: h2 = im2col(xpad) @ w1cw^T + bc  (M=32768, N=512, K=2560)
  k_gemm256<1, 2><<<256, 512, 0, stream>>>(xpad, w1cw, bc, h2, 512, 2560);
  // G2 main: cols 0..1535 (exact cover, 768 blocks = 3 full rounds)
  k_gemm256<0, 6><<<768, 512, 0, stream>>>(h2, w2b, b2, Wm, 1600, 512);
  // G2 tail: cols 1536..1599 via 128^2 kernel (B rows 1536..1663, 64 valid cols)
  k_gemm_bt<1><<<dim3(256, 1), 256, 0, stream>>>(
      h2, w2b + (size_t)1536 * 512, b2 + 1536, Wm + 1536, 512, 1600, 64);

  k_epilogue<<<8192, 256, 0, stream>>>(Wm, phone_out, phn, inv, out);
}